// Round 1
// baseline (1081.127 us; speedup 1.0000x reference)
//
#include <hip/hip_runtime.h>

#define B_ROWS 4096
#define H_DIM  2048
#define L_DIM  16384
#define TOPK   32
#define CAND_CAP 512

typedef __attribute__((ext_vector_type(8))) short bf16x8;
typedef __attribute__((ext_vector_type(4))) float f32x4;

__device__ __forceinline__ unsigned short f32_to_bf16(float f) {
  unsigned int u = __float_as_uint(f);
  u += 0x7FFFu + ((u >> 16) & 1u);           // round-to-nearest-even
  return (unsigned short)(u >> 16);
}
__device__ __forceinline__ float bf16_to_f32(unsigned short h) {
  return __uint_as_float(((unsigned int)h) << 16);
}

__device__ __forceinline__ void gload_lds16(const void* g, void* l) {
  __builtin_amdgcn_global_load_lds(
      (const __attribute__((address_space(1))) unsigned int*)g,
      (__attribute__((address_space(3))) unsigned int*)l, 16, 0, 0);
}

// ---------------------------------------------------------------- convert f32 -> bf16
__global__ __launch_bounds__(256) void k_convert(const float* __restrict__ src,
                                                 unsigned short* __restrict__ dst, int n4) {
  int i = blockIdx.x * 256 + threadIdx.x;
  if (i < n4) {
    float4 v = ((const float4*)src)[i];
    ushort4 o;
    o.x = f32_to_bf16(v.x); o.y = f32_to_bf16(v.y);
    o.z = f32_to_bf16(v.z); o.w = f32_to_bf16(v.w);
    ((ushort4*)dst)[i] = o;
  }
}

// ------------------------------------------- W_dec [H, L] f32  ->  WdT [L, H] bf16
__global__ __launch_bounds__(256) void k_transpose(const float* __restrict__ Wd,
                                                   unsigned short* __restrict__ WdT) {
  __shared__ float tile[64][65];              // [l_local][h_local], +1 pad
  int bi = blockIdx.x & 255;                  // l tile (16384/64 = 256)
  int bj = blockIdx.x >> 8;                   // h tile (2048/64 = 32)
  int t = threadIdx.x;
  int l0 = bi * 64, h0 = bj * 64;
#pragma unroll
  for (int p = 0; p < 4; ++p) {
    int hr = p * 16 + (t >> 4);
    int lc = (t & 15) * 4;
    float4 v = *(const float4*)(Wd + (size_t)(h0 + hr) * L_DIM + l0 + lc);
    tile[lc + 0][hr] = v.x; tile[lc + 1][hr] = v.y;
    tile[lc + 2][hr] = v.z; tile[lc + 3][hr] = v.w;
  }
  __syncthreads();
#pragma unroll
  for (int p = 0; p < 2; ++p) {
    int lr = p * 32 + (t >> 3);
    int hc = (t & 7) * 8;
    bf16x8 o;
#pragma unroll
    for (int i = 0; i < 8; ++i) o[i] = (short)f32_to_bf16(tile[lr][hc + i]);
    *(bf16x8*)(WdT + (size_t)(l0 + lr) * H_DIM + h0 + hc) = o;
  }
}

// ---------------------------------------------------------------- encoder GEMM (bf16 MFMA)
// A = x_bf16 [4096, 2048], Bm = W_enc_bf16 [16384, 2048] (both K-major), C = relu(A*Bm^T) fp32
__global__ __launch_bounds__(256) void k_gemm(const unsigned short* __restrict__ A,
                                              const unsigned short* __restrict__ Bm,
                                              float* __restrict__ C) {
  const int K = H_DIM, N = L_DIM;
  __shared__ unsigned short As[128 * 64];
  __shared__ unsigned short Bs[128 * 64];
  int bid = blockIdx.x;
  int cpx = gridDim.x >> 3;                              // 4096 % 8 == 0 -> bijective
  int swz = (bid & 7) * cpx + (bid >> 3);
  int tm = swz & 31;                                     // 32 M-tiles
  int tn = swz >> 5;                                     // 128 N-tiles
  int t = threadIdx.x;
  int lane = t & 63;
  int wv = t >> 6;
  int wr = wv >> 1, wc = wv & 1;

  f32x4 acc[4][4];
#pragma unroll
  for (int i = 0; i < 4; ++i)
#pragma unroll
    for (int j = 0; j < 4; ++j) { f32x4 z = {0.f, 0.f, 0.f, 0.f}; acc[i][j] = z; }

  const int rowA0 = tm * 128, rowB0 = tn * 128;
  for (int kt = 0; kt < K / 64; ++kt) {
    // stage 128x64 bf16 tiles; LDS dest linear in t (wave-uniform base + lane*16),
    // source chunk pre-swizzled (c ^ (row&7)) so swizzled ds_read reads linear data.
#pragma unroll
    for (int p = 0; p < 4; ++p) {
      int r = p * 32 + (t >> 3);
      int c = (t & 7) ^ (r & 7);
      gload_lds16(A  + (size_t)(rowA0 + r) * K + kt * 64 + c * 8, &As[p * 2048 + t * 8]);
      gload_lds16(Bm + (size_t)(rowB0 + r) * K + kt * 64 + c * 8, &Bs[p * 2048 + t * 8]);
    }
    __syncthreads();   // compiler drains vmcnt(0) before s_barrier
#pragma unroll
    for (int kk = 0; kk < 2; ++kk) {
      bf16x8 af[4], bfr[4];
      int rloc = lane & 15;
      int kc = (lane >> 4) + kk * 4;                     // chunk-of-8 within 64
#pragma unroll
      for (int m = 0; m < 4; ++m) {
        int rr = wr * 64 + m * 16 + rloc;
        af[m] = *(const bf16x8*)&As[rr * 64 + ((kc ^ (rr & 7)) << 3)];
      }
#pragma unroll
      for (int n = 0; n < 4; ++n) {
        int rr = wc * 64 + n * 16 + rloc;
        bfr[n] = *(const bf16x8*)&Bs[rr * 64 + ((kc ^ (rr & 7)) << 3)];
      }
#pragma unroll
      for (int m = 0; m < 4; ++m)
#pragma unroll
        for (int n = 0; n < 4; ++n)
          acc[m][n] = __builtin_amdgcn_mfma_f32_16x16x32_bf16(af[m], bfr[n], acc[m][n], 0, 0, 0);
    }
    __syncthreads();
  }
  // epilogue: C/D layout col=lane&15, row=(lane>>4)*4+reg  [m89]
  int colg = lane & 15;
  int rquad = lane >> 4;
#pragma unroll
  for (int m = 0; m < 4; ++m)
#pragma unroll
    for (int n = 0; n < 4; ++n) {
      int cg = tn * 128 + wc * 64 + n * 16 + colg;
#pragma unroll
      for (int r = 0; r < 4; ++r) {
        int rg = tm * 128 + wr * 64 + m * 16 + rquad * 4 + r;
        C[(size_t)rg * N + cg] = fmaxf(acc[m][n][r], 0.0f);
      }
    }
}

// ---------------------------------------------------------------- candidate selection
// Histogram only v > 2.1625 (44 bins of 0.0625 from 4.85 down) -> pick smallest edge with
// cum >= 34; collect candidates with v > edge - 0.0625 (margin >> 2*bf16-GEMM max error).
__global__ __launch_bounds__(256) void k_select(const float* __restrict__ zp,
                                                int* __restrict__ cidx, int* __restrict__ ccnt) {
  int b = blockIdx.x;
  const float4* row = (const float4*)(zp + (size_t)b * L_DIM);
  __shared__ unsigned int hist[44];
  __shared__ float s_t;
  __shared__ unsigned int s_cnt;
  int t = threadIdx.x;
  if (t < 44) hist[t] = 0;
  if (t == 0) s_cnt = 0;
  __syncthreads();
  for (int i = t; i < L_DIM / 4; i += 256) {
    float4 v = row[i];
    float vv[4] = {v.x, v.y, v.z, v.w};
#pragma unroll
    for (int q = 0; q < 4; ++q) {
      float f = vv[q];
      if (f > 2.1625f) {
        int j = (int)floorf((4.85f - f) * 16.0f) + 1;
        j = j < 0 ? 0 : (j > 43 ? 43 : j);
        atomicAdd(&hist[j], 1u);
      }
    }
  }
  __syncthreads();
  if (t == 0) {
    unsigned int cum = 0; float tsel = -1.0f;
    for (int j = 0; j < 44; ++j) {
      cum += hist[j];
      if (cum >= 34) { tsel = 4.85f - 0.0625f * j - 0.0625f; break; }
    }
    s_t = tsel;
  }
  __syncthreads();
  float tsel = s_t;
  if (tsel < 0.0f) {                                    // pathological fallback (never for this data)
    float tt = 2.1625f;
    for (int iter = 0; iter < 16 && tsel < 0.0f; ++iter) {
      tt -= 0.25f; if (tt < 0.f) tt = 0.f;
      if (t == 0) s_cnt = 0;
      __syncthreads();
      unsigned int local = 0;
      for (int i = t; i < L_DIM / 4; i += 256) {
        float4 v = row[i];
        if (v.x > tt) local++; if (v.y > tt) local++;
        if (v.z > tt) local++; if (v.w > tt) local++;
      }
      atomicAdd(&s_cnt, local);
      __syncthreads();
      if (s_cnt >= 34 || tt == 0.f) tsel = tt;
      __syncthreads();
    }
  }
  if (t == 0) s_cnt = 0;
  __syncthreads();
  for (int i = t; i < L_DIM / 4; i += 256) {
    float4 v = row[i];
    float vv[4] = {v.x, v.y, v.z, v.w};
#pragma unroll
    for (int q = 0; q < 4; ++q) {
      if (vv[q] > tsel) {
        unsigned int p = atomicAdd(&s_cnt, 1u);
        if (p < CAND_CAP) cidx[b * CAND_CAP + p] = i * 4 + q;
      }
    }
  }
  __syncthreads();
  if (t == 0) ccnt[b] = (int)(s_cnt < CAND_CAP ? s_cnt : CAND_CAP);
}

// ------------------------------------- exact rescore of candidates (fp32 inputs, fp64 accum)
__global__ __launch_bounds__(256) void k_recompute(const float* __restrict__ x,
                                                   const float* __restrict__ Wenc,
                                                   const int* __restrict__ cidx,
                                                   const int* __restrict__ ccnt,
                                                   double* __restrict__ cval) {
  int b = blockIdx.x;
  __shared__ float xr[H_DIM];
  int t = threadIdx.x;
  const float4* xv = (const float4*)(x + (size_t)b * H_DIM);
  for (int i = t; i < H_DIM / 4; i += 256) ((float4*)xr)[i] = xv[i];
  __syncthreads();
  int cnt = ccnt[b];
  int wv = t >> 6, lane = t & 63;
  for (int c = wv; c < cnt; c += 4) {
    int l = cidx[b * CAND_CAP + c];
    const float4* wrow = (const float4*)(Wenc + (size_t)l * H_DIM);
    double acc = 0.0;
#pragma unroll
    for (int k8 = 0; k8 < 8; ++k8) {
      float4 w = wrow[k8 * 64 + lane];
      float4 xx = ((const float4*)xr)[k8 * 64 + lane];
      acc += (double)w.x * xx.x + (double)w.y * xx.y + (double)w.z * xx.z + (double)w.w * xx.w;
    }
#pragma unroll
    for (int s = 32; s; s >>= 1) acc += __shfl_xor(acc, s, 64);
    if (lane == 0) cval[b * CAND_CAP + c] = acc;
  }
}

// ------------------------------- top-32 among exact candidates; scatter z; emit (idx,val) list
__global__ __launch_bounds__(64) void k_finalize(const int* __restrict__ cidx,
                                                 const double* __restrict__ cval,
                                                 const int* __restrict__ ccnt,
                                                 float* __restrict__ zout,
                                                 float* __restrict__ selv, int* __restrict__ seli) {
  int b = blockIdx.x;
  int lane = threadIdx.x;
  __shared__ double dv[CAND_CAP];
  __shared__ int di[CAND_CAP];
  int cnt = ccnt[b]; if (cnt > CAND_CAP) cnt = CAND_CAP;
  for (int i = lane; i < cnt; i += 64) { dv[i] = cval[b * CAND_CAP + i]; di[i] = cidx[b * CAND_CAP + i]; }
  __syncthreads();
  for (int s = 0; s < TOPK; ++s) {
    double bv = -1.0e300; int bi = 0x7fffffff;
    for (int i = lane; i < cnt; i += 64) {
      double vi = dv[i]; int ii = di[i];
      if (vi > bv || (vi == bv && ii < bi)) { bv = vi; bi = ii; }
    }
#pragma unroll
    for (int sh = 32; sh; sh >>= 1) {
      double ov = __shfl_xor(bv, sh, 64);
      int oi = __shfl_xor(bi, sh, 64);
      if (ov > bv || (ov == bv && oi < bi)) { bv = ov; bi = oi; }
    }
    bool valid = (s < cnt) && (bv > 0.0);
    if (lane == 0) {
      selv[b * TOPK + s] = valid ? (float)bv : 0.0f;
      seli[b * TOPK + s] = valid ? bi : 0;
      if (valid) zout[(size_t)b * L_DIM + bi] = (float)bv;
    }
    for (int i = lane; i < cnt; i += 64) if (di[i] == bi) dv[i] = -1.0e300;
    __syncthreads();
  }
}

// ---------------------------------------------------------------- sparse decoder
__global__ __launch_bounds__(256) void k_decoder(const unsigned short* __restrict__ WdT,
                                                 const float* __restrict__ selv,
                                                 const int* __restrict__ seli,
                                                 float* __restrict__ xhat) {
  int b = blockIdx.x;
  int t = threadIdx.x;
  __shared__ float sv[TOPK];
  __shared__ int si[TOPK];
  if (t < TOPK) { sv[t] = selv[b * TOPK + t]; si[t] = seli[b * TOPK + t]; }
  __syncthreads();
  float acc[8] = {0.f, 0.f, 0.f, 0.f, 0.f, 0.f, 0.f, 0.f};
  for (int j = 0; j < TOPK; ++j) {
    float vj = sv[j];
    bf16x8 w = *(const bf16x8*)(WdT + (size_t)si[j] * H_DIM + t * 8);
#pragma unroll
    for (int i = 0; i < 8; ++i) acc[i] += vj * bf16_to_f32((unsigned short)w[i]);
  }
  float4 o0 = {acc[0], acc[1], acc[2], acc[3]};
  float4 o1 = {acc[4], acc[5], acc[6], acc[7]};
  float4* op = (float4*)(xhat + (size_t)b * H_DIM + t * 8);
  op[0] = o0; op[1] = o1;
}

extern "C" void kernel_launch(void* const* d_in, const int* in_sizes, int n_in,
                              void* d_out, int out_size, void* d_ws, size_t ws_size,
                              hipStream_t stream) {
  const float* x    = (const float*)d_in[0];
  const float* Wenc = (const float*)d_in[1];
  const float* Wdec = (const float*)d_in[2];
  // d_in[3] = topk (=32), hardcoded

  float* xhat = (float*)d_out;
  float* z    = (float*)d_out + (size_t)B_ROWS * H_DIM;

  char* ws = (char*)d_ws;
  if (ws_size < 177225728u) return;  // need ~169 MB scratch
  unsigned short* xbf    = (unsigned short*)(ws);                 // 16,777,216 B
  unsigned short* Wencbf = (unsigned short*)(ws + 16777216);      // 67,108,864 B
  unsigned short* WdT    = (unsigned short*)(ws + 83886080);      // 67,108,864 B
  int*    cidx = (int*)   (ws + 150994944);                       //  8,388,608 B
  double* cval = (double*)(ws + 159383552);                       // 16,777,216 B
  int*    ccnt = (int*)   (ws + 176160768);                       //     16,384 B
  float*  selv = (float*) (ws + 176177152);                       //    524,288 B
  int*    seli = (int*)   (ws + 176701440);                       //    524,288 B

  k_convert<<<(2097152 + 255) / 256, 256, 0, stream>>>(x, xbf, 2097152);
  k_convert<<<(8388608 + 255) / 256, 256, 0, stream>>>(Wenc, Wencbf, 8388608);
  k_transpose<<<8192, 256, 0, stream>>>(Wdec, WdT);
  k_gemm<<<4096, 256, 0, stream>>>(xbf, Wencbf, z);               // z holds relu'd z_pre (scratch)
  k_select<<<B_ROWS, 256, 0, stream>>>(z, cidx, ccnt);
  k_recompute<<<B_ROWS, 256, 0, stream>>>(x, Wenc, cidx, ccnt, cval);
  hipMemsetAsync(z, 0, (size_t)B_ROWS * L_DIM * sizeof(float), stream);
  k_finalize<<<B_ROWS, 64, 0, stream>>>(cidx, cval, ccnt, z, selv, seli);
  k_decoder<<<B_ROWS, 256, 0, stream>>>(WdT, selv, seli, xhat);
}

// Round 2
// 829.659 us; speedup vs baseline: 1.3031x; 1.3031x over previous
//
#include <hip/hip_runtime.h>

#define B_ROWS 4096
#define H_DIM  2048
#define L_DIM  16384
#define TOPK   32
#define CAND_CAP 512

// GEMM geometry: 256x256 tile, BK=32, 512 threads (8 waves, 2x4), 3-slot LDS ring
#define GBM 256
#define GBN 256
#define GBK 32
#define GNT (H_DIM / GBK)   // 64 K-tiles

typedef __attribute__((ext_vector_type(8))) short bf16x8;
typedef __attribute__((ext_vector_type(4))) float f32x4;

__device__ __forceinline__ unsigned short f32_to_bf16(float f) {
  unsigned int u = __float_as_uint(f);
  u += 0x7FFFu + ((u >> 16) & 1u);           // round-to-nearest-even
  return (unsigned short)(u >> 16);
}
__device__ __forceinline__ float bf16_to_f32(unsigned short h) {
  return __uint_as_float(((unsigned int)h) << 16);
}

__device__ __forceinline__ void gload_lds16(const void* g, void* l) {
  __builtin_amdgcn_global_load_lds(
      (const __attribute__((address_space(1))) unsigned int*)g,
      (__attribute__((address_space(3))) unsigned int*)l, 16, 0, 0);
}

// ---------------------------------------------------------------- convert f32 -> bf16
__global__ __launch_bounds__(256) void k_convert(const float* __restrict__ src,
                                                 unsigned short* __restrict__ dst, int n4) {
  int i = blockIdx.x * 256 + threadIdx.x;
  if (i < n4) {
    float4 v = ((const float4*)src)[i];
    ushort4 o;
    o.x = f32_to_bf16(v.x); o.y = f32_to_bf16(v.y);
    o.z = f32_to_bf16(v.z); o.w = f32_to_bf16(v.w);
    ((ushort4*)dst)[i] = o;
  }
}

// ------------------------------------------- W_dec [H, L] f32  ->  WdT [L, H] bf16
__global__ __launch_bounds__(256) void k_transpose(const float* __restrict__ Wd,
                                                   unsigned short* __restrict__ WdT) {
  __shared__ float tile[64][65];              // [l_local][h_local], +1 pad
  int bi = blockIdx.x & 255;                  // l tile (16384/64 = 256)
  int bj = blockIdx.x >> 8;                   // h tile (2048/64 = 32)
  int t = threadIdx.x;
  int l0 = bi * 64, h0 = bj * 64;
#pragma unroll
  for (int p = 0; p < 4; ++p) {
    int hr = p * 16 + (t >> 4);
    int lc = (t & 15) * 4;
    float4 v = *(const float4*)(Wd + (size_t)(h0 + hr) * L_DIM + l0 + lc);
    tile[lc + 0][hr] = v.x; tile[lc + 1][hr] = v.y;
    tile[lc + 2][hr] = v.z; tile[lc + 3][hr] = v.w;
  }
  __syncthreads();
#pragma unroll
  for (int p = 0; p < 2; ++p) {
    int lr = p * 32 + (t >> 3);
    int hc = (t & 7) * 8;
    bf16x8 o;
#pragma unroll
    for (int i = 0; i < 8; ++i) o[i] = (short)f32_to_bf16(tile[lr][hc + i]);
    *(bf16x8*)(WdT + (size_t)(l0 + lr) * H_DIM + h0 + hc) = o;
  }
}

// ---------------------------------------------------------------- encoder GEMM (bf16 MFMA)
// A = x_bf16 [4096, 2048], Bm = W_enc_bf16 [16384, 2048] (K-major), Zp = bf16(relu(A*Bm^T))
// 3-slot LDS ring, 2 phases/tile, counted vmcnt(4) at tile boundaries (never 0 in main loop).
__global__ __launch_bounds__(512, 2) void k_gemm(const unsigned short* __restrict__ A,
                                                 const unsigned short* __restrict__ Bm,
                                                 unsigned short* __restrict__ Zp) {
  __shared__ unsigned short As[3 * 8192];     // 3 x 256x32 bf16 = 48 KB
  __shared__ unsigned short Bs[3 * 8192];     // 48 KB
  const size_t K = H_DIM;
  int bid = blockIdx.x;
  int cpx = gridDim.x >> 3;                   // 1024/8 = 128, bijective (nwg%8==0)
  int swz = (bid & 7) * cpx + (bid >> 3);
  int tm = swz >> 6;                          // 16 M-tiles; XCD chunk shares one A panel
  int tn = swz & 63;                          // 64 N-tiles
  int t = threadIdx.x;
  int lane = t & 63;
  int w = t >> 6;
  int wm = w >> 2, wn = w & 3;                // 2 x 4 wave grid; per-wave 128x64

  int rloc = lane & 15;
  int kc = lane >> 4;                         // 0..3 : 8-elem K chunk
  int swzk = (kc ^ ((rloc >> 1) & 3)) << 3;   // bank swizzle (2-way max), shorts

  // staging decode: per thread row = j*128 + (t>>2), phys chunk (t&3) holds logical kcs
  int srow = t >> 2;
  int kcs = (t & 3) ^ ((srow >> 1) & 3);      // inverse-permuted global source (rule 21)
  const unsigned short* aS0 = A + (size_t)(tm * GBM + srow) * K + kcs * 8;
  const unsigned short* aS1 = aS0 + 128 * K;
  const unsigned short* bS0 = Bm + (size_t)(tn * GBN + srow) * K + kcs * 8;
  const unsigned short* bS1 = bS0 + 128 * K;
  int dA = t * 8;                             // linear LDS dest (shorts): wave base + lane*16B

  f32x4 acc[8][4];
#pragma unroll
  for (int i = 0; i < 8; ++i)
#pragma unroll
    for (int j = 0; j < 4; ++j) { f32x4 z = {0.f, 0.f, 0.f, 0.f}; acc[i][j] = z; }

#define STAGE_A(kt, sw) { size_t ko = (size_t)(kt) * GBK; \
    gload_lds16(aS0 + ko, &As[(sw) * 8192 + dA]); \
    gload_lds16(aS1 + ko, &As[(sw) * 8192 + 4096 + dA]); }
#define STAGE_B(kt, sw) { size_t ko = (size_t)(kt) * GBK; \
    gload_lds16(bS0 + ko, &Bs[(sw) * 8192 + dA]); \
    gload_lds16(bS1 + ko, &Bs[(sw) * 8192 + 4096 + dA]); }

  // prologue: stage tile0 + tile1 (8 loads/wave); wait tile0 (4 outstanding allowed)
  STAGE_A(0, 0) STAGE_B(0, 0)
  STAGE_A(1, 1) STAGE_B(1, 1)
  asm volatile("s_waitcnt vmcnt(4)" ::: "memory");
  __builtin_amdgcn_s_barrier();

  int sR = 0;
  const int aBase0 = (wm * 128 + rloc) * 32 + swzk;
  const int bBase0 = (wn * 64 + rloc) * 32 + swzk;
  for (int kt = 0; kt < GNT; ++kt) {
    int sW = sR + 2; if (sW >= 3) sW -= 3;
    const unsigned short* Ab = &As[sR * 8192 + aBase0];
    const unsigned short* Bb = &Bs[sR * 8192 + bBase0];
    bool st = (kt + 2 < GNT);                 // wave-uniform
    // ---- phase 0: read A-half0 + all B frags; issue A-stage of tile kt+2
    bf16x8 a0[4], b0[4];
#pragma unroll
    for (int m = 0; m < 4; ++m) a0[m] = *(const bf16x8*)(Ab + m * 512);
#pragma unroll
    for (int n = 0; n < 4; ++n) b0[n] = *(const bf16x8*)(Bb + n * 512);
    if (st) STAGE_A(kt + 2, sW)
    __builtin_amdgcn_s_barrier();
    __builtin_amdgcn_s_setprio(1);
#pragma unroll
    for (int m = 0; m < 4; ++m)
#pragma unroll
      for (int n = 0; n < 4; ++n)
        acc[m][n] = __builtin_amdgcn_mfma_f32_16x16x32_bf16(a0[m], b0[n], acc[m][n], 0, 0, 0);
    __builtin_amdgcn_s_setprio(0);
    __builtin_amdgcn_s_barrier();
    // ---- phase 1: read A-half1 (B reused); issue B-stage of tile kt+2
    bf16x8 a1[4];
#pragma unroll
    for (int m = 0; m < 4; ++m) a1[m] = *(const bf16x8*)(Ab + (m + 4) * 512);
    if (st) STAGE_B(kt + 2, sW)
    __builtin_amdgcn_s_barrier();
    __builtin_amdgcn_s_setprio(1);
#pragma unroll
    for (int m = 0; m < 4; ++m)
#pragma unroll
      for (int n = 0; n < 4; ++n)
        acc[m + 4][n] = __builtin_amdgcn_mfma_f32_16x16x32_bf16(a1[m], b0[n], acc[m + 4][n], 0, 0, 0);
    __builtin_amdgcn_s_setprio(0);
    // ---- tile boundary: counted wait — tile kt+1 landed, tile kt+2 (4 loads) in flight
    if (kt < GNT - 2) { asm volatile("s_waitcnt vmcnt(4)" ::: "memory"); }
    else if (kt == GNT - 2) { asm volatile("s_waitcnt vmcnt(0)" ::: "memory"); }
    __builtin_amdgcn_s_barrier();
    ++sR; if (sR == 3) sR = 0;
  }
#undef STAGE_A
#undef STAGE_B
  // epilogue: C/D layout col=lane&15, row=(lane>>4)*4+reg [m89]; relu + bf16
  int colg = lane & 15, quad = lane >> 4;
  size_t rbase = (size_t)(tm * GBM + wm * 128 + quad * 4);
  int cbase = tn * GBN + wn * 64 + colg;
#pragma unroll
  for (int m = 0; m < 8; ++m)
#pragma unroll
    for (int n = 0; n < 4; ++n) {
      size_t rr = rbase + m * 16;
      int cc = cbase + n * 16;
#pragma unroll
      for (int r = 0; r < 4; ++r)
        Zp[(rr + r) * L_DIM + cc] = f32_to_bf16(fmaxf(acc[m][n][r], 0.0f));
    }
}

// ---------------------------------------------------------------- candidate selection (bf16 z_pre)
// Histogram v > 2.1625 (44 bins of 0.0625 from 4.85 down) -> smallest edge with cum >= 34;
// collect v > edge - 0.0625. Margin 0.0625 > 2*(bf16-GEMM err 0.013 + bf16 quant 0.016).
__global__ __launch_bounds__(256) void k_select(const unsigned short* __restrict__ zp,
                                                int* __restrict__ cidx, int* __restrict__ ccnt) {
  int b = blockIdx.x;
  const bf16x8* row = (const bf16x8*)(zp + (size_t)b * L_DIM);
  __shared__ unsigned int hist[44];
  __shared__ float s_t;
  __shared__ unsigned int s_cnt;
  int t = threadIdx.x;
  if (t < 44) hist[t] = 0;
  if (t == 0) s_cnt = 0;
  __syncthreads();
  for (int i = t; i < L_DIM / 8; i += 256) {
    bf16x8 v = row[i];
#pragma unroll
    for (int q = 0; q < 8; ++q) {
      float f = bf16_to_f32((unsigned short)v[q]);
      if (f > 2.1625f) {
        int j = (int)floorf((4.85f - f) * 16.0f) + 1;
        j = j < 0 ? 0 : (j > 43 ? 43 : j);
        atomicAdd(&hist[j], 1u);
      }
    }
  }
  __syncthreads();
  if (t == 0) {
    unsigned int cum = 0; float tsel = -1.0f;
    for (int j = 0; j < 44; ++j) {
      cum += hist[j];
      if (cum >= 34) { tsel = 4.85f - 0.0625f * j - 0.0625f; break; }
    }
    s_t = tsel;
  }
  __syncthreads();
  float tsel = s_t;
  if (tsel < 0.0f) {                          // pathological fallback (never for this data)
    float tt = 2.1625f;
    for (int iter = 0; iter < 16 && tsel < 0.0f; ++iter) {
      tt -= 0.25f; if (tt < 0.f) tt = 0.f;
      if (t == 0) s_cnt = 0;
      __syncthreads();
      unsigned int local = 0;
      for (int i = t; i < L_DIM / 8; i += 256) {
        bf16x8 v = row[i];
#pragma unroll
        for (int q = 0; q < 8; ++q) if (bf16_to_f32((unsigned short)v[q]) > tt) local++;
      }
      atomicAdd(&s_cnt, local);
      __syncthreads();
      if (s_cnt >= 34 || tt == 0.f) tsel = tt;
      __syncthreads();
    }
  }
  if (t == 0) s_cnt = 0;
  __syncthreads();
  for (int i = t; i < L_DIM / 8; i += 256) {
    bf16x8 v = row[i];
#pragma unroll
    for (int q = 0; q < 8; ++q) {
      if (bf16_to_f32((unsigned short)v[q]) > tsel) {
        unsigned int p = atomicAdd(&s_cnt, 1u);
        if (p < CAND_CAP) cidx[b * CAND_CAP + p] = i * 8 + q;
      }
    }
  }
  __syncthreads();
  if (t == 0) ccnt[b] = (int)(s_cnt < CAND_CAP ? s_cnt : CAND_CAP);
}

// ------------------------------------- exact rescore of candidates (fp32 inputs, fp64 accum)
__global__ __launch_bounds__(256) void k_recompute(const float* __restrict__ x,
                                                   const float* __restrict__ Wenc,
                                                   const int* __restrict__ cidx,
                                                   const int* __restrict__ ccnt,
                                                   double* __restrict__ cval) {
  int b = blockIdx.x;
  __shared__ float xr[H_DIM];
  int t = threadIdx.x;
  const float4* xv = (const float4*)(x + (size_t)b * H_DIM);
  for (int i = t; i < H_DIM / 4; i += 256) ((float4*)xr)[i] = xv[i];
  __syncthreads();
  int cnt = ccnt[b];
  int wv = t >> 6, lane = t & 63;
  for (int c = wv; c < cnt; c += 4) {
    int l = cidx[b * CAND_CAP + c];
    const float4* wrow = (const float4*)(Wenc + (size_t)l * H_DIM);
    double acc = 0.0;
#pragma unroll
    for (int k8 = 0; k8 < 8; ++k8) {
      float4 w = wrow[k8 * 64 + lane];
      float4 xx = ((const float4*)xr)[k8 * 64 + lane];
      acc += (double)w.x * xx.x + (double)w.y * xx.y + (double)w.z * xx.z + (double)w.w * xx.w;
    }
#pragma unroll
    for (int s = 32; s; s >>= 1) acc += __shfl_xor(acc, s, 64);
    if (lane == 0) cval[b * CAND_CAP + c] = acc;
  }
}

// ------------------------------- top-32 among exact candidates; scatter z; emit (idx,val) list
__global__ __launch_bounds__(64) void k_finalize(const int* __restrict__ cidx,
                                                 const double* __restrict__ cval,
                                                 const int* __restrict__ ccnt,
                                                 float* __restrict__ zout,
                                                 float* __restrict__ selv, int* __restrict__ seli) {
  int b = blockIdx.x;
  int lane = threadIdx.x;
  __shared__ double dv[CAND_CAP];
  __shared__ int di[CAND_CAP];
  int cnt = ccnt[b]; if (cnt > CAND_CAP) cnt = CAND_CAP;
  for (int i = lane; i < cnt; i += 64) { dv[i] = cval[b * CAND_CAP + i]; di[i] = cidx[b * CAND_CAP + i]; }
  __syncthreads();
  for (int s = 0; s < TOPK; ++s) {
    double bv = -1.0e300; int bi = 0x7fffffff;
    for (int i = lane; i < cnt; i += 64) {
      double vi = dv[i]; int ii = di[i];
      if (vi > bv || (vi == bv && ii < bi)) { bv = vi; bi = ii; }
    }
#pragma unroll
    for (int sh = 32; sh; sh >>= 1) {
      double ov = __shfl_xor(bv, sh, 64);
      int oi = __shfl_xor(bi, sh, 64);
      if (ov > bv || (ov == bv && oi < bi)) { bv = ov; bi = oi; }
    }
    bool valid = (s < cnt) && (bv > 0.0);
    if (lane == 0) {
      selv[b * TOPK + s] = valid ? (float)bv : 0.0f;
      seli[b * TOPK + s] = valid ? bi : 0;
      if (valid) zout[(size_t)b * L_DIM + bi] = (float)bv;
    }
    for (int i = lane; i < cnt; i += 64) if (di[i] == bi) dv[i] = -1.0e300;
    __syncthreads();
  }
}

// ---------------------------------------------------------------- sparse decoder
__global__ __launch_bounds__(256) void k_decoder(const unsigned short* __restrict__ WdT,
                                                 const float* __restrict__ selv,
                                                 const int* __restrict__ seli,
                                                 float* __restrict__ xhat) {
  int b = blockIdx.x;
  int t = threadIdx.x;
  __shared__ float sv[TOPK];
  __shared__ int si[TOPK];
  if (t < TOPK) { sv[t] = selv[b * TOPK + t]; si[t] = seli[b * TOPK + t]; }
  __syncthreads();
  float acc[8] = {0.f, 0.f, 0.f, 0.f, 0.f, 0.f, 0.f, 0.f};
  for (int j = 0; j < TOPK; ++j) {
    float vj = sv[j];
    bf16x8 w = *(const bf16x8*)(WdT + (size_t)si[j] * H_DIM + t * 8);
#pragma unroll
    for (int i = 0; i < 8; ++i) acc[i] += vj * bf16_to_f32((unsigned short)w[i]);
  }
  float4 o0 = {acc[0], acc[1], acc[2], acc[3]};
  float4 o1 = {acc[4], acc[5], acc[6], acc[7]};
  float4* op = (float4*)(xhat + (size_t)b * H_DIM + t * 8);
  op[0] = o0; op[1] = o1;
}

extern "C" void kernel_launch(void* const* d_in, const int* in_sizes, int n_in,
                              void* d_out, int out_size, void* d_ws, size_t ws_size,
                              hipStream_t stream) {
  const float* x    = (const float*)d_in[0];
  const float* Wenc = (const float*)d_in[1];
  const float* Wdec = (const float*)d_in[2];
  // d_in[3] = topk (=32), hardcoded

  float* xhat = (float*)d_out;
  float* z    = (float*)d_out + (size_t)B_ROWS * H_DIM;

  char* ws = (char*)d_ws;
  if (ws_size < 177225728u) return;  // need ~169 MB scratch
  unsigned short* xbf    = (unsigned short*)(ws);                 // 16,777,216 B
  unsigned short* Wencbf = (unsigned short*)(ws + 16777216);      // 67,108,864 B
  unsigned short* WdT    = (unsigned short*)(ws + 83886080);      // 67,108,864 B
  int*    cidx = (int*)   (ws + 150994944);                       //  8,388,608 B
  double* cval = (double*)(ws + 159383552);                       // 16,777,216 B
  int*    ccnt = (int*)   (ws + 176160768);                       //     16,384 B
  float*  selv = (float*) (ws + 176177152);                       //    524,288 B
  int*    seli = (int*)   (ws + 176701440);                       //    524,288 B

  unsigned short* zpre = (unsigned short*)z;                      // bf16 scratch in z region

  k_convert<<<(2097152 + 255) / 256, 256, 0, stream>>>(x, xbf, 2097152);
  k_convert<<<(8388608 + 255) / 256, 256, 0, stream>>>(Wenc, Wencbf, 8388608);
  k_transpose<<<8192, 256, 0, stream>>>(Wdec, WdT);
  k_gemm<<<1024, 512, 0, stream>>>(xbf, Wencbf, zpre);            // bf16 relu'd z_pre
  k_select<<<B_ROWS, 256, 0, stream>>>(zpre, cidx, ccnt);
  k_recompute<<<B_ROWS, 256, 0, stream>>>(x, Wenc, cidx, ccnt, cval);
  hipMemsetAsync(z, 0, (size_t)B_ROWS * L_DIM * sizeof(float), stream);
  k_finalize<<<B_ROWS, 64, 0, stream>>>(cidx, cval, ccnt, z, selv, seli);
  k_decoder<<<B_ROWS, 256, 0, stream>>>(WdT, selv, seli, xhat);
}